// Round 5
// baseline (268.347 us; speedup 1.0000x reference)
//
#include <hip/hip_runtime.h>

#define HW    262144      // 512*512
#define HW2   131072      // HW/2
#define NPIX  2097152     // 8*512*512
#define NG2   (NPIX / 2)  // float2 pixel-groups
#define CNEW  21
#define COLD  16

// ---------- pass 1: bitmask of classes present in masks ----------
__global__ __launch_bounds__(256)
void lgod_present_scan(const int4* __restrict__ m4,
                       unsigned int* __restrict__ pm) {
    unsigned int local = 0;
    const int stride = gridDim.x * blockDim.x;
    for (int p = blockIdx.x * blockDim.x + threadIdx.x; p < NPIX / 4; p += stride) {
        int4 v = m4[p];
        if (v.x >= 1 && v.x < CNEW) local |= (1u << v.x);
        if (v.y >= 1 && v.y < CNEW) local |= (1u << v.y);
        if (v.z >= 1 && v.z < CNEW) local |= (1u << v.z);
        if (v.w >= 1 && v.w < CNEW) local |= (1u << v.w);
    }
    #pragma unroll
    for (int off = 32; off; off >>= 1) local |= __shfl_down(local, off);
    __shared__ unsigned int sm;
    if (threadIdx.x == 0) sm = 0;
    __syncthreads();
    if ((threadIdx.x & 63) == 0 && local) atomicOr(&sm, local);
    __syncthreads();
    if (threadIdx.x == 0 && sm) atomicOr(pm, sm);
}

// ---------- pass 2: fused loss, 2 px/thread, channel-rotated, fused finalize ----------
__global__ __launch_bounds__(256)
void lgod_main(const float2* __restrict__ inp2,   // [8,21,HW/2]
               const float2* __restrict__ tgt2,   // [8,16,HW/2]
               const int2*   __restrict__ masks2, // [NG2]
               const unsigned int* __restrict__ pm_p,
               double* __restrict__ accum,
               unsigned int* __restrict__ counter,
               float* __restrict__ out) {
    const unsigned int pm = *pm_p;
    const int t   = blockIdx.x * blockDim.x + threadIdx.x;  // 0 .. NG2-1
    const int b   = t >> 17;
    const int hw2 = t & (HW2 - 1);
    const float2* ip = inp2 + (size_t)b * CNEW * HW2 + hw2;
    const float2* tp = tgt2 + (size_t)b * COLD * HW2 + hw2;

    const int2 mv = masks2[t];
    int ma[2] = {mv.x, mv.y};
    int mm[2];
    #pragma unroll
    for (int j = 0; j < 2; ++j)
        mm[j] = (ma[j] == 0 || ma[j] == 255) ? 0 : ma[j];

    float se[2] = {0,0};   // sum exp(inputs)
    float st[2] = {0,0};   // sum exp(targets)
    float P[2]  = {0,0};   // sum_absent in[c]*exp(t[c])
    float Q[2]  = {0,0};   // sum_absent exp(t[c])
    float t0e[2] = {0,0};  // exp(t[0])
    float vm[2] = {0,0};   // in[mm]

    // block-uniform channel rotation to decorrelate the 1-MiB-strided streams
    const int rot_t = blockIdx.x & (COLD - 1);
    const int rot_i = blockIdx.x % CNEW;

    #pragma unroll
    for (int k = 0; k < COLD; ++k) {
        int c = k + rot_t; c &= (COLD - 1);
        float2 tv = tp[(size_t)c * HW2];
        float ta[2] = {tv.x, tv.y};
        const bool absent = (c >= 1) && !((pm >> c) & 1u);  // wave-uniform
        const bool is0 = (c == 0);
        #pragma unroll
        for (int j = 0; j < 2; ++j) {
            float e = __expf(ta[j]);
            st[j] += e;
            if (is0) t0e[j] = e;
            if (absent) Q[j] += e;
        }
        if (absent) {   // need matching input channel for P (c < 16 here)
            float2 iv = ip[(size_t)c * HW2];
            P[0] += iv.x * __expf(ta[0]);
            P[1] += iv.y * __expf(ta[1]);
        }
    }
    #pragma unroll
    for (int k = 0; k < CNEW; ++k) {
        int c = k + rot_i; if (c >= CNEW) c -= CNEW;
        float2 iv = ip[(size_t)c * HW2];
        float ia[2] = {iv.x, iv.y};
        #pragma unroll
        for (int j = 0; j < 2; ++j) {
            se[j] += __expf(ia[j]);
            vm[j] = (c == mm[j]) ? ia[j] : vm[j];
        }
    }

    float acc = 0.f;
    #pragma unroll
    for (int j = 0; j < 2; ++j) {
        float lse = __logf(se[j]);
        float inv = 1.0f / st[j];
        float S = 0.f;
        if (ma[j] < CNEW || ma[j] == 255)     // valid label -> out[mm]*labels0
            S = (vm[j] - lse) * t0e[j];
        S += P[j] - lse * Q[j];               // absent-class channels (0 if none)
        acc += S * inv;
    }

    // wave reduce -> block reduce -> one double atomic per block
    #pragma unroll
    for (int off = 32; off; off >>= 1) acc += __shfl_down(acc, off);
    __shared__ float warp_s[4];
    __shared__ bool amLast;
    const int wid = threadIdx.x >> 6;
    if ((threadIdx.x & 63) == 0) warp_s[wid] = acc;
    __syncthreads();
    if (threadIdx.x == 0) {
        float tot = warp_s[0] + warp_s[1] + warp_s[2] + warp_s[3];
        atomicAdd(accum, (double)tot);
        __threadfence();
        unsigned int c = atomicAdd(counter, 1u);
        amLast = (c == gridDim.x - 1);
    }
    __syncthreads();
    if (amLast && threadIdx.x == 0) {
        __threadfence();
        double v = atomicAdd(accum, 0.0);     // coherent read of final sum
        out[0] = (float)(-v / ((double)CNEW * (double)NPIX));
    }
}

extern "C" void kernel_launch(void* const* d_in, const int* in_sizes, int n_in,
                              void* d_out, int out_size, void* d_ws, size_t ws_size,
                              hipStream_t stream) {
    const float2* inp2   = (const float2*)d_in[0];
    const float2* tgt2   = (const float2*)d_in[1];
    const int*    masks  = (const int*)d_in[2];
    float* out = (float*)d_out;

    double* accum        = (double*)d_ws;                       // 8 B
    unsigned int* pm     = (unsigned int*)((char*)d_ws + 8);    // 4 B
    unsigned int* counter= (unsigned int*)((char*)d_ws + 12);   // 4 B

    hipMemsetAsync(d_ws, 0, 16, stream);
    lgod_present_scan<<<1024, 256, 0, stream>>>((const int4*)masks, pm);
    lgod_main<<<NG2 / 256, 256, 0, stream>>>(inp2, (const float2*)d_in[1],
                                             (const int2*)masks, pm, accum,
                                             counter, out);
    (void)out_size; (void)ws_size; (void)n_in; (void)in_sizes;
}

// Round 6
// 92.386 us; speedup vs baseline: 2.9046x; 2.9046x over previous
//
#include <hip/hip_runtime.h>

#define HW    262144      // 512*512
#define NPIX  2097152     // 8*512*512
#define CNEW  21
#define COLD  16
#define NBLK  2048
#define NTHR  256

// Single-pass fused loss.
//   loss_sum = main_acc + sum_{c=1..15, c absent} T_c
// where T_c = sum_pix (in[c]-lse)*softmax_t[c] is accumulated unconditionally
// and the presence bitmask (from masks) gates T_c in the finalize kernel.
// Channel order is uniform across all blocks: the launch-order convoy makes
// the whole chip sweep one channel region at a time (DRAM row locality —
// R5 showed breaking this costs 2.5x).
__global__ __launch_bounds__(256)
void lgod_main(const float* __restrict__ inp,   // [8,21,HW]
               const float* __restrict__ tgt,   // [8,16,HW]
               const int*   __restrict__ masks, // [NPIX]
               double* __restrict__ accum,      // ws: main accumulator
               float*  __restrict__ Tc,         // ws: 15 channel corrections
               unsigned int* __restrict__ pmp)  // ws: presence bitmask
{
    float tacc[15];
    #pragma unroll
    for (int i = 0; i < 15; ++i) tacc[i] = 0.f;
    float macc = 0.f;
    unsigned int pbits = 0;

    const int stride = NBLK * NTHR;
    for (int p = blockIdx.x * NTHR + threadIdx.x; p < NPIX; p += stride) {
        const int b  = p >> 18;
        const int hw = p & (HW - 1);
        const float* ipx = inp + (size_t)b * CNEW * HW + hw;
        const float* tpx = tgt + (size_t)b * COLD * HW + hw;
        const int m = masks[p];
        if (m >= 1 && m < CNEW) pbits |= (1u << m);

        // targets: e[c] = exp(t[c]), st = sum (max-free: inputs are O(1) normals)
        float e[COLD];
        float st = 0.f;
        #pragma unroll
        for (int c = 0; c < COLD; ++c) {
            e[c] = __expf(tpx[(size_t)c * HW]);
            st += e[c];
        }

        // inputs: se = sum exp(in), vm = in[mm], keep in[1..15] for T_c
        const int mm = (m == 0 || m == 255) ? 0 : m;
        float ikeep[15];
        float x0 = ipx[0];
        float se = __expf(x0);
        float vm = x0;
        #pragma unroll
        for (int c = 1; c < COLD; ++c) {
            float x = ipx[(size_t)c * HW];
            ikeep[c - 1] = x;
            se += __expf(x);
            vm = (c == mm) ? x : vm;
        }
        #pragma unroll
        for (int c = COLD; c < CNEW; ++c) {
            float x = ipx[(size_t)c * HW];
            se += __expf(x);
            vm = (c == mm) ? x : vm;
        }

        const float lse = __logf(se);
        const float inv = 1.0f / st;
        if (m < CNEW || m == 255)            // valid or ignore label -> main term
            macc += (vm - lse) * e[0] * inv;
        #pragma unroll
        for (int c = 1; c < COLD; ++c)       // unconditional channel corrections
            tacc[c - 1] += (ikeep[c - 1] - lse) * e[c] * inv;
    }

    // ---- reductions: wave butterfly -> LDS -> per-block atomics ----
    #pragma unroll
    for (int off = 32; off; off >>= 1) macc += __shfl_down(macc, off);
    #pragma unroll
    for (int i = 0; i < 15; ++i) {
        #pragma unroll
        for (int off = 32; off; off >>= 1) tacc[i] += __shfl_down(tacc[i], off);
    }
    #pragma unroll
    for (int off = 32; off; off >>= 1) pbits |= __shfl_down(pbits, off);

    __shared__ float s_m[4];
    __shared__ float s_t[4][15];
    __shared__ unsigned int s_p;
    if (threadIdx.x == 0) s_p = 0;
    __syncthreads();
    const int wid = threadIdx.x >> 6;
    if ((threadIdx.x & 63) == 0) {
        s_m[wid] = macc;
        #pragma unroll
        for (int i = 0; i < 15; ++i) s_t[wid][i] = tacc[i];
        if (pbits) atomicOr(&s_p, pbits);
    }
    __syncthreads();
    if (threadIdx.x == 0) {
        atomicAdd(accum, (double)(s_m[0] + s_m[1] + s_m[2] + s_m[3]));
        if (s_p) atomicOr(pmp, s_p);
    }
    if (threadIdx.x < 15) {                  // 15 parallel per-block atomics
        const int i = threadIdx.x;
        atomicAdd(&Tc[i], s_t[0][i] + s_t[1][i] + s_t[2][i] + s_t[3][i]);
    }
}

// ---- finalize: apply presence gate, scale, negate ----
__global__ void lgod_finalize(const double* __restrict__ accum,
                              const float* __restrict__ Tc,
                              const unsigned int* __restrict__ pmp,
                              float* __restrict__ out) {
    double v = accum[0];
    const unsigned int pm = pmp[0];
    for (int c = 1; c < COLD; ++c)
        if (!((pm >> c) & 1u)) v += (double)Tc[c - 1];
    out[0] = (float)(-v / ((double)CNEW * (double)NPIX));
}

extern "C" void kernel_launch(void* const* d_in, const int* in_sizes, int n_in,
                              void* d_out, int out_size, void* d_ws, size_t ws_size,
                              hipStream_t stream) {
    const float* inp   = (const float*)d_in[0];
    const float* tgt   = (const float*)d_in[1];
    const int*   masks = (const int*)d_in[2];
    float* out = (float*)d_out;

    double* accum    = (double*)d_ws;                        // 8 B
    float*  Tc       = (float*)((char*)d_ws + 8);            // 60 B
    unsigned int* pm = (unsigned int*)((char*)d_ws + 68);    // 4 B

    hipMemsetAsync(d_ws, 0, 128, stream);
    lgod_main<<<NBLK, NTHR, 0, stream>>>(inp, tgt, masks, accum, Tc, pm);
    lgod_finalize<<<1, 1, 0, stream>>>(accum, Tc, pm, out);
    (void)out_size; (void)ws_size; (void)n_in; (void)in_sizes;
}